// Round 9
// baseline (290.578 us; speedup 1.0000x reference)
//
#include <hip/hip_runtime.h>
#include <hip/hip_bf16.h>

#define NEG_SLOPE 0.2f

typedef __attribute__((ext_vector_type(4))) float f32x4;
typedef __attribute__((ext_vector_type(8))) short s16x8;

__device__ __forceinline__ short f2bf(float x) {
    __hip_bfloat16 h = __float2bfloat16(x);
    return *reinterpret_cast<short*>(&h);
}

// ---------- 1) k_proj: MFMA bf16 GEMM + fused el/er epilogue ----------
#define PCHUNK 64
__global__ __launch_bounds__(256) void k_proj(const float* __restrict__ feat,
                                              const float* __restrict__ Wfc,
                                              __hip_bfloat16* __restrict__ fsrcb,
                                              const float* __restrict__ attn_l,
                                              const float* __restrict__ attn_r,
                                              const int* __restrict__ ntype,
                                              float* __restrict__ el,
                                              float* __restrict__ er, int n) {
    __shared__ short Wb[128 * 128];          // 32 KB
    __shared__ float s_al[512], s_ar[512];   // 4 KB attn tables
    const int t = threadIdx.x;
    for (int idx = t; idx < 128 * 128; idx += 256) {
        int c = idx >> 7, k = idx & 127;
        Wb[c * 128 + ((((k >> 3) ^ (c & 7)) << 3) | (k & 7))] = f2bf(Wfc[idx]);
    }
    s_al[t] = attn_l[t]; s_al[t + 256] = attn_l[t + 256];
    s_ar[t] = attn_r[t]; s_ar[t + 256] = attn_r[t + 256];
    __syncthreads();

    const int w   = t >> 6;
    const int l   = t & 63;
    const int c16 = l & 15;
    const int g0  = l >> 4;
    const int nchunks = (n + PCHUNK - 1) / PCHUNK;

    for (int chunk = blockIdx.x; chunk < nchunks; chunk += gridDim.x) {
        const int rbase = chunk * PCHUNK + w * 16;
        const float* ap = feat + (size_t)min(rbase + c16, n - 1) * 128;
        s16x8 av[4];
        #pragma unroll
        for (int kq = 0; kq < 4; ++kq) {
            float4 q0 = *(const float4*)(ap + g0 * 8 + kq * 32);
            float4 q1 = *(const float4*)(ap + g0 * 8 + kq * 32 + 4);
            s16x8 a;
            a[0] = f2bf(q0.x); a[1] = f2bf(q0.y); a[2] = f2bf(q0.z); a[3] = f2bf(q0.w);
            a[4] = f2bf(q1.x); a[5] = f2bf(q1.y); a[6] = f2bf(q1.z); a[7] = f2bf(q1.w);
            av[kq] = a;
        }
        f32x4 acc[8];
        #pragma unroll
        for (int f = 0; f < 8; ++f) acc[f] = (f32x4)0.f;
        #pragma unroll
        for (int kq = 0; kq < 4; ++kq) {
            const int g = g0 + kq * 4;
            #pragma unroll
            for (int f = 0; f < 8; ++f) {
                const int c = f * 16 + c16;
                const s16x8 bv = *(const s16x8*)&Wb[c * 128 + ((g ^ (c & 7)) << 3)];
                acc[f] = __builtin_amdgcn_mfma_f32_16x16x32_bf16(av[kq], bv, acc[f], 0, 0, 0);
            }
        }
        #pragma unroll
        for (int reg = 0; reg < 4; ++reg) {
            const int rr = rbase + g0 * 4 + reg;
            const bool ok = rr < n;
            if (ok) {
                #pragma unroll
                for (int f = 0; f < 8; ++f)
                    fsrcb[(size_t)rr * 128 + f * 16 + c16] = __float2bfloat16(acc[f][reg]);
            }
            const int nt = ntype[min(rr, n - 1)];
            const float* alp = s_al + nt * 128;
            const float* arp = s_ar + nt * 128;
            float pe[4], pr[4];
            #pragma unroll
            for (int h = 0; h < 4; ++h) {
                float d0 = acc[2 * h][reg], d1 = acc[2 * h + 1][reg];
                pe[h] = d0 * alp[h * 32 + c16] + d1 * alp[h * 32 + 16 + c16];
                pr[h] = d0 * arp[h * 32 + c16] + d1 * arp[h * 32 + 16 + c16];
            }
            #pragma unroll
            for (int msk = 1; msk < 16; msk <<= 1) {
                #pragma unroll
                for (int h = 0; h < 4; ++h) {
                    pe[h] += __shfl_xor(pe[h], msk, 64);
                    pr[h] += __shfl_xor(pr[h], msk, 64);
                }
            }
            if (c16 == 0 && ok) {
                float4 e4; e4.x = pe[0]; e4.y = pe[1]; e4.z = pe[2]; e4.w = pe[3];
                float4 r4; r4.x = pr[0]; r4.y = pr[1]; r4.z = pr[2]; r4.w = pr[3];
                *(float4*)(el + (size_t)rr * 4) = e4;
                *(float4*)(er + (size_t)rr * 4) = r4;
            }
        }
    }
}

// ---------- 2) degree histogram + fused ee table (block 0) ----------
__global__ void k_deg(const int* __restrict__ dst, int* __restrict__ deg, int ne,
                      const float* __restrict__ W_e, const float* __restrict__ edge_emb,
                      const float* __restrict__ attn_e, float* __restrict__ eet) {
    if (blockIdx.x == 0 && threadIdx.x < 32) {
        int t = threadIdx.x;
        int et = t >> 2, h = t & 3;
        float ee = 0.f;
        for (int f = 0; f < 32; ++f) {
            float acc = 0.f;
            for (int g = 0; g < 32; ++g)
                acc += W_e[((size_t)h * 32 + f) * 32 + g] * edge_emb[et * 32 + g];
            ee += acc * attn_e[((size_t)et * 4 + h) * 32 + f];
        }
        eet[t] = ee * (float)et;
    }
    int e = blockIdx.x * blockDim.x + threadIdx.x;
    if (e < ne) atomicAdd(deg + dst[e], 1);
}

// ---------- 3) hierarchical exclusive scan: deg -> offs[n+1], cursor ----------
#define SC_ELEMS 1024
__global__ __launch_bounds__(256) void k_scan_sum(const int* __restrict__ deg,
                                                  int* __restrict__ bsum, int n) {
    __shared__ int red[256];
    const int t = threadIdx.x;
    const int base = blockIdx.x * SC_ELEMS;
    int s = 0;
    #pragma unroll
    for (int i = 0; i < 4; ++i) {
        int idx = base + t * 4 + i;
        if (idx < n) s += deg[idx];
    }
    red[t] = s;
    __syncthreads();
    for (int off = 128; off > 0; off >>= 1) {
        if (t < off) red[t] += red[t + off];
        __syncthreads();
    }
    if (t == 0) bsum[blockIdx.x] = red[0];
}

__global__ __launch_bounds__(1024) void k_scan_mid(int* __restrict__ bsum, int nb) {
    __shared__ int sh[1024];
    const int t = threadIdx.x;
    int v = (t < nb) ? bsum[t] : 0;
    sh[t] = v;
    __syncthreads();
    for (int off = 1; off < 1024; off <<= 1) {
        int add = (t >= off) ? sh[t - off] : 0;
        __syncthreads();
        sh[t] += add;
        __syncthreads();
    }
    if (t < nb) bsum[t] = sh[t] - v;   // exclusive
}

__global__ __launch_bounds__(256) void k_scan_out(const int* __restrict__ deg,
                                                  const int* __restrict__ bsum,
                                                  int* __restrict__ offs,
                                                  int* __restrict__ cursor, int n) {
    __shared__ int sh[256];
    const int t = threadIdx.x;
    const int base = blockIdx.x * SC_ELEMS + t * 4;
    int v[4], s = 0;
    #pragma unroll
    for (int i = 0; i < 4; ++i) {
        int idx = base + i;
        v[i] = (idx < n) ? deg[idx] : 0;
        s += v[i];
    }
    sh[t] = s;
    __syncthreads();
    const int mine = s;
    for (int off = 1; off < 256; off <<= 1) {
        int add = (t >= off) ? sh[t - off] : 0;
        __syncthreads();
        sh[t] += add;
        __syncthreads();
    }
    int run = bsum[blockIdx.x] + sh[t] - mine;
    #pragma unroll
    for (int i = 0; i < 4; ++i) {
        int idx = base + i;
        if (idx < n) { offs[idx] = run; cursor[idx] = run; run += v[i]; }
    }
    if (blockIdx.x == gridDim.x - 1 && t == 255) offs[n] = run;
}

// ---------- 4) k_edge: scatter 8B payload {e|etype<<24, src} into CSR ----------
__global__ void k_edge(const int* __restrict__ src, const int* __restrict__ dst,
                       const int* __restrict__ etype, int* __restrict__ cursor,
                       int2* __restrict__ pay, int ne) {
    int e = blockIdx.x * blockDim.x + threadIdx.x;
    if (e >= ne) return;
    int d = dst[e];
    int pos = atomicAdd(cursor + d, 1);
    int2 p; p.x = e | (etype[e] << 24); p.y = src[e];
    pay[pos] = p;
}

// ---------- 5) per-dst softmax + aggregate ----------
// 128 threads/node. lane l of wave w owns col pair (2l, 2l+1); wave w does edges k%2==w.
#define CHUNK 128
__global__ __launch_bounds__(128) void k_aggfull(const int* __restrict__ offs,
                                                 const int2* __restrict__ pay,
                                                 const float* __restrict__ el,
                                                 const float* __restrict__ er,
                                                 const float* __restrict__ eet,
                                                 const __hip_bfloat16* __restrict__ fsrcb,
                                                 float* __restrict__ aBuf,
                                                 float* __restrict__ rst) {
    __shared__ int   s_eid[CHUNK];
    __shared__ int   s_src[CHUNK];
    __shared__ float s_sc[4][CHUNK + 1];
    __shared__ float s_p[4][CHUNK + 1];
    __shared__ float s_eet[32];
    __shared__ float s_red[128];
    __shared__ float s_mr[8];          // m[0..3], rden[4..7]
    const int d = blockIdx.x;
    const int j = threadIdx.x;
    const int w = j >> 6;
    const int l = j & 63;
    const int l16 = l & 15;
    const int h2 = l >> 4;             // head of this lane's col pair
    if (j < 32) s_eet[j] = eet[j];
    const int b = offs[d], e1 = offs[d + 1];
    const int deg = e1 - b;
    float4 er4 = *(const float4*)(er + (size_t)d * 4);
    __syncthreads();

    float mOld = -1e30f, den = 0.f, acc0 = 0.f, acc1 = 0.f;
    for (int c0 = 0; c0 < deg; c0 += CHUNK) {
        const int cn = min(CHUNK, deg - c0);
        if (j < cn) {
            int2 p2 = pay[b + c0 + j];
            int e = p2.x & 0xFFFFFF, et = p2.x >> 24, s = p2.y;
            s_eid[j] = e; s_src[j] = s;
            float4 lv = *(const float4*)(el + (size_t)s * 4);
            const float* te = s_eet + et * 4;
            float4 v;
            v.x = lv.x + er4.x + te[0];
            v.y = lv.y + er4.y + te[1];
            v.z = lv.z + er4.z + te[2];
            v.w = lv.w + er4.w + te[3];
            v.x = v.x > 0.f ? v.x : NEG_SLOPE * v.x;
            v.y = v.y > 0.f ? v.y : NEG_SLOPE * v.y;
            v.z = v.z > 0.f ? v.z : NEG_SLOPE * v.z;
            v.w = v.w > 0.f ? v.w : NEG_SLOPE * v.w;
            s_sc[0][j] = v.x; s_sc[1][j] = v.y; s_sc[2][j] = v.z; s_sc[3][j] = v.w;
        }
        __syncthreads();
        // running max per head (16-lane groups; both waves redundant)
        float mc = mOld;
        for (int k = l16; k < cn; k += 16) mc = fmaxf(mc, s_sc[h2][k]);
        #pragma unroll
        for (int msk = 1; msk < 16; msk <<= 1) mc = fmaxf(mc, __shfl_xor(mc, msk, 64));
        float scale = __expf(mOld - mc);    // first chunk: exp(-inf)=0; den/acc are 0
        den *= scale; acc0 *= scale; acc1 *= scale;
        if (w == 0 && l16 == 0) s_mr[h2] = mc;
        mOld = mc;
        __syncthreads();
        if (j < cn) {
            s_p[0][j] = __expf(s_sc[0][j] - s_mr[0]);
            s_p[1][j] = __expf(s_sc[1][j] - s_mr[1]);
            s_p[2][j] = __expf(s_sc[2][j] - s_mr[2]);
            s_p[3][j] = __expf(s_sc[3][j] - s_mr[3]);
        }
        __syncthreads();
        float dc = 0.f;
        for (int k = l16; k < cn; k += 16) dc += s_p[h2][k];
        #pragma unroll
        for (int msk = 1; msk < 16; msk <<= 1) dc += __shfl_xor(dc, msk, 64);
        den += dc;
        // gather: dword bf16x2 per edge, wave w takes edges k%2==w
        for (int k = w; k < cn; k += 2) {
            unsigned u = *(const unsigned*)(fsrcb + (size_t)s_src[k] * 128 + 2 * l);
            float lo = __uint_as_float(u << 16);
            float hi = __uint_as_float(u & 0xFFFF0000u);
            float p = s_p[h2][k];
            acc0 = fmaf(p, lo, acc0);
            acc1 = fmaf(p, hi, acc1);
        }
        __syncthreads();
    }
    float rden = (den > 0.f) ? 1.f / den : 0.f;
    // cross-wave combine + store
    if (w == 1) { s_red[2 * l] = acc0; s_red[2 * l + 1] = acc1; }
    if (w == 0 && l16 == 0) s_mr[4 + h2] = rden;
    __syncthreads();
    if (w == 0) {
        float2 o;
        o.x = (acc0 + s_red[2 * l]) * rden;
        o.y = (acc1 + s_red[2 * l + 1]) * rden;
        *(float2*)(rst + (size_t)d * 128 + 2 * l) = o;
    }

    if (deg <= CHUNK) {
        if (j < deg) {
            float4 a;
            a.x = s_p[0][j] * s_mr[4];
            a.y = s_p[1][j] * s_mr[5];
            a.z = s_p[2][j] * s_mr[6];
            a.w = s_p[3][j] * s_mr[7];
            *(float4*)(aBuf + (size_t)s_eid[j] * 4) = a;
        }
    } else {
        for (int k0 = 0; k0 < deg; k0 += CHUNK) {
            int k = k0 + j;
            if (k < deg) {
                int2 p2 = pay[b + k];
                int e = p2.x & 0xFFFFFF, et = p2.x >> 24, s = p2.y;
                float4 lv = *(const float4*)(el + (size_t)s * 4);
                const float* te = s_eet + et * 4;
                float4 v;
                v.x = lv.x + er4.x + te[0];
                v.y = lv.y + er4.y + te[1];
                v.z = lv.z + er4.z + te[2];
                v.w = lv.w + er4.w + te[3];
                v.x = v.x > 0.f ? v.x : NEG_SLOPE * v.x;
                v.y = v.y > 0.f ? v.y : NEG_SLOPE * v.y;
                v.z = v.z > 0.f ? v.z : NEG_SLOPE * v.z;
                v.w = v.w > 0.f ? v.w : NEG_SLOPE * v.w;
                float4 a;
                a.x = __expf(v.x - s_mr[0]) * s_mr[4];
                a.y = __expf(v.y - s_mr[1]) * s_mr[5];
                a.z = __expf(v.z - s_mr[2]) * s_mr[6];
                a.w = __expf(v.w - s_mr[3]) * s_mr[7];
                *(float4*)(aBuf + (size_t)e * 4) = a;
            }
        }
    }
}

extern "C" void kernel_launch(void* const* d_in, const int* in_sizes, int n_in,
                              void* d_out, int out_size, void* d_ws, size_t ws_size,
                              hipStream_t stream) {
    const float* feat     = (const float*)d_in[0];
    const float* W_fc     = (const float*)d_in[1];
    const float* W_e      = (const float*)d_in[2];
    const float* edge_emb = (const float*)d_in[3];
    const float* attn_l   = (const float*)d_in[4];
    const float* attn_r   = (const float*)d_in[5];
    const float* attn_e   = (const float*)d_in[6];
    const int* src   = (const int*)d_in[7];
    const int* dst   = (const int*)d_in[8];
    const int* etype = (const int*)d_in[9];
    const int* ntype = (const int*)d_in[10];
    const int n  = in_sizes[0] / 128;
    const int ne = in_sizes[7];

    // workspace layout
    __hip_bfloat16* fsrcb = (__hip_bfloat16*)d_ws;     // n*128 bf16
    int2* pay   = (int2*)(fsrcb + (size_t)n * 128);    // ne int2 (8B payload)
    float* el   = (float*)(pay + ne);                  // n*4 f
    float* er   = el + (size_t)n * 4;                  // n*4 f
    float* eet  = er + (size_t)n * 4;                  // 32 f
    int* deg    = (int*)(eet + 32);                    // n i
    int* offs   = deg + n;                             // n+1 i
    int* cursor = offs + n + 1;                        // n i
    int* bsum   = cursor + n;                          // <=1024 i

    float* rst  = (float*)d_out;                       // n*128
    float* aBuf = rst + (size_t)n * 128;               // ne*4 (final a)

    const int nb = (n + SC_ELEMS - 1) / SC_ELEMS;

    hipMemsetAsync(deg, 0, (size_t)n * sizeof(int), stream);

    k_proj<<<512, 256, 0, stream>>>(feat, W_fc, fsrcb, attn_l, attn_r, ntype, el, er, n);
    k_deg<<<(ne + 255) / 256, 256, 0, stream>>>(dst, deg, ne, W_e, edge_emb, attn_e, eet);
    k_scan_sum<<<nb, 256, 0, stream>>>(deg, bsum, n);
    k_scan_mid<<<1, 1024, 0, stream>>>(bsum, nb);
    k_scan_out<<<nb, 256, 0, stream>>>(deg, bsum, offs, cursor, n);
    k_edge<<<(ne + 255) / 256, 256, 0, stream>>>(src, dst, etype, cursor, pay, ne);
    k_aggfull<<<n, 128, 0, stream>>>(offs, pay, el, er, eet, fsrcb, aBuf, rst);
}

// Round 11
// 258.492 us; speedup vs baseline: 1.1241x; 1.1241x over previous
//
#include <hip/hip_runtime.h>
#include <hip/hip_bf16.h>

#define NEG_SLOPE 0.2f

typedef __attribute__((ext_vector_type(4))) float f32x4;
typedef __attribute__((ext_vector_type(8))) short s16x8;
typedef __attribute__((ext_vector_type(4))) short s16x4;

__device__ __forceinline__ short f2bf(float x) {
    __hip_bfloat16 h = __float2bfloat16(x);
    return *reinterpret_cast<short*>(&h);
}

// ---------- 1) k_proj: MFMA bf16 GEMM (swapped operands -> row-major frags) ----------
// chunk = 64 rows; wave w owns rows [chunk*64 + w*16, +16).
// acc[f] = mfma(W-frag, feat-frag): lane (c16,g0) holds fsrc[row rbase+c16]
// cols f*16 + g0*4 + reg  -> 8B stores, cheap el/er epilogue (2 shfl steps).
#define PCHUNK 64
__global__ __launch_bounds__(256) void k_proj(const float* __restrict__ feat,
                                              const float* __restrict__ Wfc,
                                              __hip_bfloat16* __restrict__ fsrcb,
                                              const float* __restrict__ attn_l,
                                              const float* __restrict__ attn_r,
                                              const int* __restrict__ ntype,
                                              float* __restrict__ el,
                                              float* __restrict__ er, int n) {
    __shared__ short Wb[128 * 128];          // 32 KB, swizzled [c][k]
    __shared__ float s_al[512], s_ar[512];   // 4 KB attn tables
    const int t = threadIdx.x;
    for (int idx = t; idx < 128 * 128; idx += 256) {
        int c = idx >> 7, k = idx & 127;
        Wb[c * 128 + ((((k >> 3) ^ (c & 7)) << 3) | (k & 7))] = f2bf(Wfc[idx]);
    }
    s_al[t] = attn_l[t]; s_al[t + 256] = attn_l[t + 256];
    s_ar[t] = attn_r[t]; s_ar[t + 256] = attn_r[t + 256];
    __syncthreads();

    const int w   = t >> 6;
    const int l   = t & 63;
    const int c16 = l & 15;        // row within 16-row group
    const int g0  = l >> 4;        // k-group / col-quad selector
    const int nchunks = (n + PCHUNK - 1) / PCHUNK;

    for (int chunk = blockIdx.x; chunk < nchunks; chunk += gridDim.x) {
        const int rbase = chunk * PCHUNK + w * 16;
        const int rr = rbase + c16;           // this lane's output row
        const float* ap = feat + (size_t)min(rr, n - 1) * 128;
        s16x8 av[4];
        #pragma unroll
        for (int kq = 0; kq < 4; ++kq) {
            float4 q0 = *(const float4*)(ap + g0 * 8 + kq * 32);
            float4 q1 = *(const float4*)(ap + g0 * 8 + kq * 32 + 4);
            s16x8 a;
            a[0] = f2bf(q0.x); a[1] = f2bf(q0.y); a[2] = f2bf(q0.z); a[3] = f2bf(q0.w);
            a[4] = f2bf(q1.x); a[5] = f2bf(q1.y); a[6] = f2bf(q1.z); a[7] = f2bf(q1.w);
            av[kq] = a;
        }
        f32x4 acc[8];
        #pragma unroll
        for (int f = 0; f < 8; ++f) acc[f] = (f32x4)0.f;
        #pragma unroll
        for (int kq = 0; kq < 4; ++kq) {
            const int g = g0 + kq * 4;
            #pragma unroll
            for (int f = 0; f < 8; ++f) {
                const int c = f * 16 + c16;    // W row (A-operand row)
                const s16x8 bv = *(const s16x8*)&Wb[c * 128 + ((g ^ (c & 7)) << 3)];
                // swapped: A=W rows, B=feat^T  ->  D = fsrc^T fragment
                acc[f] = __builtin_amdgcn_mfma_f32_16x16x32_bf16(bv, av[kq], acc[f], 0, 0, 0);
            }
        }
        const bool ok = rr < n;
        // store: 4 consecutive bf16 cols per frag (8B)
        if (ok) {
            #pragma unroll
            for (int f = 0; f < 8; ++f) {
                s16x4 pk;
                pk[0] = f2bf(acc[f][0]); pk[1] = f2bf(acc[f][1]);
                pk[2] = f2bf(acc[f][2]); pk[3] = f2bf(acc[f][3]);
                *(s16x4*)&fsrcb[(size_t)rr * 128 + f * 16 + g0 * 4] = pk;
            }
        }
        // el/er: lane's cols are f*16+g0*4+reg; head h = f>>1
        const int nt = ntype[min(rr, n - 1)];
        float pe[4], pr[4];
        #pragma unroll
        for (int h = 0; h < 4; ++h) {
            float4 a0 = *(const float4*)&s_al[nt * 128 + (2 * h) * 16 + g0 * 4];
            float4 a1 = *(const float4*)&s_al[nt * 128 + (2 * h + 1) * 16 + g0 * 4];
            float4 r0 = *(const float4*)&s_ar[nt * 128 + (2 * h) * 16 + g0 * 4];
            float4 r1 = *(const float4*)&s_ar[nt * 128 + (2 * h + 1) * 16 + g0 * 4];
            f32x4 dA = acc[2 * h], dB = acc[2 * h + 1];
            pe[h] = dA[0]*a0.x + dA[1]*a0.y + dA[2]*a0.z + dA[3]*a0.w
                  + dB[0]*a1.x + dB[1]*a1.y + dB[2]*a1.z + dB[3]*a1.w;
            pr[h] = dA[0]*r0.x + dA[1]*r0.y + dA[2]*r0.z + dA[3]*r0.w
                  + dB[0]*r1.x + dB[1]*r1.y + dB[2]*r1.z + dB[3]*r1.w;
        }
        #pragma unroll
        for (int h = 0; h < 4; ++h) {
            pe[h] += __shfl_xor(pe[h], 16, 64);
            pe[h] += __shfl_xor(pe[h], 32, 64);
            pr[h] += __shfl_xor(pr[h], 16, 64);
            pr[h] += __shfl_xor(pr[h], 32, 64);
        }
        if (g0 == 0 && ok) {
            float4 e4; e4.x = pe[0]; e4.y = pe[1]; e4.z = pe[2]; e4.w = pe[3];
            float4 r4; r4.x = pr[0]; r4.y = pr[1]; r4.z = pr[2]; r4.w = pr[3];
            *(float4*)(el + (size_t)rr * 4) = e4;
            *(float4*)(er + (size_t)rr * 4) = r4;
        }
    }
}

// ---------- 2) degree histogram + fused ee table (block 0) ----------
__global__ void k_deg(const int* __restrict__ dst, int* __restrict__ deg, int ne,
                      const float* __restrict__ W_e, const float* __restrict__ edge_emb,
                      const float* __restrict__ attn_e, float* __restrict__ eet) {
    if (blockIdx.x == 0 && threadIdx.x < 32) {
        int t = threadIdx.x;
        int et = t >> 2, h = t & 3;
        float ee = 0.f;
        for (int f = 0; f < 32; ++f) {
            float acc = 0.f;
            for (int g = 0; g < 32; ++g)
                acc += W_e[((size_t)h * 32 + f) * 32 + g] * edge_emb[et * 32 + g];
            ee += acc * attn_e[((size_t)et * 4 + h) * 32 + f];
        }
        eet[t] = ee * (float)et;
    }
    int e = blockIdx.x * blockDim.x + threadIdx.x;
    if (e < ne) atomicAdd(deg + dst[e], 1);
}

// ---------- 3) hierarchical exclusive scan: deg -> offs[n+1], cursor ----------
#define SC_ELEMS 1024
__global__ __launch_bounds__(256) void k_scan_sum(const int* __restrict__ deg,
                                                  int* __restrict__ bsum, int n) {
    __shared__ int red[256];
    const int t = threadIdx.x;
    const int base = blockIdx.x * SC_ELEMS;
    int s = 0;
    #pragma unroll
    for (int i = 0; i < 4; ++i) {
        int idx = base + t * 4 + i;
        if (idx < n) s += deg[idx];
    }
    red[t] = s;
    __syncthreads();
    for (int off = 128; off > 0; off >>= 1) {
        if (t < off) red[t] += red[t + off];
        __syncthreads();
    }
    if (t == 0) bsum[blockIdx.x] = red[0];
}

__global__ __launch_bounds__(1024) void k_scan_mid(int* __restrict__ bsum, int nb) {
    __shared__ int sh[1024];
    const int t = threadIdx.x;
    int v = (t < nb) ? bsum[t] : 0;
    sh[t] = v;
    __syncthreads();
    for (int off = 1; off < 1024; off <<= 1) {
        int add = (t >= off) ? sh[t - off] : 0;
        __syncthreads();
        sh[t] += add;
        __syncthreads();
    }
    if (t < nb) bsum[t] = sh[t] - v;   // exclusive
}

__global__ __launch_bounds__(256) void k_scan_out(const int* __restrict__ deg,
                                                  const int* __restrict__ bsum,
                                                  int* __restrict__ offs,
                                                  int* __restrict__ cursor, int n) {
    __shared__ int sh[256];
    const int t = threadIdx.x;
    const int base = blockIdx.x * SC_ELEMS + t * 4;
    int v[4], s = 0;
    #pragma unroll
    for (int i = 0; i < 4; ++i) {
        int idx = base + i;
        v[i] = (idx < n) ? deg[idx] : 0;
        s += v[i];
    }
    sh[t] = s;
    __syncthreads();
    const int mine = s;
    for (int off = 1; off < 256; off <<= 1) {
        int add = (t >= off) ? sh[t - off] : 0;
        __syncthreads();
        sh[t] += add;
        __syncthreads();
    }
    int run = bsum[blockIdx.x] + sh[t] - mine;
    #pragma unroll
    for (int i = 0; i < 4; ++i) {
        int idx = base + i;
        if (idx < n) { offs[idx] = run; cursor[idx] = run; run += v[i]; }
    }
    if (blockIdx.x == gridDim.x - 1 && t == 255) offs[n] = run;
}

// ---------- 4) k_edge: scores + leaky relu + scatter 32B payload into CSR ----------
__global__ void k_edge(const int* __restrict__ src, const int* __restrict__ dst,
                       const int* __restrict__ etype, const float* __restrict__ el,
                       const float* __restrict__ er, const float* __restrict__ eet,
                       int* __restrict__ cursor, float* __restrict__ pay, int ne) {
    int e = blockIdx.x * blockDim.x + threadIdx.x;
    if (e >= ne) return;
    int s = src[e], d = dst[e], et = etype[e];
    float4 l = *(const float4*)(el + (size_t)s * 4);
    float4 r = *(const float4*)(er + (size_t)d * 4);
    float4 te = *(const float4*)(eet + (size_t)et * 4);
    float4 v;
    v.x = l.x + r.x + te.x;
    v.y = l.y + r.y + te.y;
    v.z = l.z + r.z + te.z;
    v.w = l.w + r.w + te.w;
    v.x = v.x > 0.f ? v.x : NEG_SLOPE * v.x;
    v.y = v.y > 0.f ? v.y : NEG_SLOPE * v.y;
    v.z = v.z > 0.f ? v.z : NEG_SLOPE * v.z;
    v.w = v.w > 0.f ? v.w : NEG_SLOPE * v.w;
    int pos = atomicAdd(cursor + d, 1);
    *(float4*)(pay + (size_t)pos * 8) = v;
    int2 es; es.x = e; es.y = s;
    *(int2*)(pay + (size_t)pos * 8 + 4) = es;
}

// ---------- 5) per-dst softmax + aggregate (round-8 proven form) ----------
#define CHUNK 128
__global__ __launch_bounds__(128) void k_aggfull(const int* __restrict__ offs,
                                                 const float* __restrict__ pay,
                                                 const __hip_bfloat16* __restrict__ fsrcb,
                                                 float* __restrict__ aBuf,
                                                 float* __restrict__ rst) {
    __shared__ int   s_src[CHUNK];
    __shared__ int   s_eid[CHUNK];
    __shared__ float s_sc[4][CHUNK];
    __shared__ float s_p[4][CHUNK];
    __shared__ float s_mr[8];          // m[0..3], rden[4..7]
    const int d = blockIdx.x;
    const int j = threadIdx.x;
    const int h = j >> 5;
    const int b = offs[d], e1 = offs[d + 1];
    const int deg = e1 - b;

    float m = -1e30f, den = 0.f, acc = 0.f;
    for (int c0 = 0; c0 < deg; c0 += CHUNK) {
        const int cn = min(CHUNK, deg - c0);
        if (j < cn) {   // linear payload read (coalesced)
            const float* p8 = pay + (size_t)(b + c0 + j) * 8;
            float4 v = *(const float4*)p8;
            int2 es = *(const int2*)(p8 + 4);
            s_sc[0][j] = v.x; s_sc[1][j] = v.y; s_sc[2][j] = v.z; s_sc[3][j] = v.w;
            s_eid[j] = es.x; s_src[j] = es.y;
        }
        __syncthreads();
        float mc = -1e30f;
        for (int k = j & 31; k < cn; k += 32) mc = fmaxf(mc, s_sc[h][k]);
        #pragma unroll
        for (int w = 1; w < 32; w <<= 1) mc = fmaxf(mc, __shfl_xor(mc, w, 64));
        mc = fmaxf(mc, m);
        float scale = __expf(m - mc);
        den *= scale; acc *= scale; m = mc;
        if ((j & 31) == 0) s_mr[h] = m;
        __syncthreads();
        if (j < cn) {
            s_p[0][j] = __expf(s_sc[0][j] - s_mr[0]);
            s_p[1][j] = __expf(s_sc[1][j] - s_mr[1]);
            s_p[2][j] = __expf(s_sc[2][j] - s_mr[2]);
            s_p[3][j] = __expf(s_sc[3][j] - s_mr[3]);
        }
        __syncthreads();
        float dc = 0.f;
        for (int k = j & 31; k < cn; k += 32) dc += s_p[h][k];
        #pragma unroll
        for (int w = 1; w < 32; w <<= 1) dc += __shfl_xor(dc, w, 64);
        den += dc;
        #pragma unroll 4
        for (int k = 0; k < cn; ++k) {
            acc = fmaf(s_p[h][k],
                       __bfloat162float(fsrcb[(size_t)s_src[k] * 128 + j]), acc);
        }
        __syncthreads();
    }
    float rden = (den > 0.f) ? 1.f / den : 0.f;
    rst[(size_t)d * 128 + j] = acc * rden;

    if ((j & 31) == 0) s_mr[4 + h] = rden;
    __syncthreads();

    if (deg <= CHUNK) {
        if (j < deg) {
            float4 a;
            a.x = s_p[0][j] * s_mr[4];
            a.y = s_p[1][j] * s_mr[5];
            a.z = s_p[2][j] * s_mr[6];
            a.w = s_p[3][j] * s_mr[7];
            *(float4*)(aBuf + (size_t)s_eid[j] * 4) = a;
        }
    } else {
        for (int k0 = 0; k0 < deg; k0 += CHUNK) {
            int k = k0 + j;
            if (k < deg) {
                const float* p8 = pay + (size_t)(b + k) * 8;
                float4 v = *(const float4*)p8;
                int e = *(const int*)(p8 + 4);
                float4 a;
                a.x = __expf(v.x - s_mr[0]) * s_mr[4];
                a.y = __expf(v.y - s_mr[1]) * s_mr[5];
                a.z = __expf(v.z - s_mr[2]) * s_mr[6];
                a.w = __expf(v.w - s_mr[3]) * s_mr[7];
                *(float4*)(aBuf + (size_t)e * 4) = a;
            }
        }
    }
}

extern "C" void kernel_launch(void* const* d_in, const int* in_sizes, int n_in,
                              void* d_out, int out_size, void* d_ws, size_t ws_size,
                              hipStream_t stream) {
    const float* feat     = (const float*)d_in[0];
    const float* W_fc     = (const float*)d_in[1];
    const float* W_e      = (const float*)d_in[2];
    const float* edge_emb = (const float*)d_in[3];
    const float* attn_l   = (const float*)d_in[4];
    const float* attn_r   = (const float*)d_in[5];
    const float* attn_e   = (const float*)d_in[6];
    const int* src   = (const int*)d_in[7];
    const int* dst   = (const int*)d_in[8];
    const int* etype = (const int*)d_in[9];
    const int* ntype = (const int*)d_in[10];
    const int n  = in_sizes[0] / 128;
    const int ne = in_sizes[7];

    // workspace layout
    __hip_bfloat16* fsrcb = (__hip_bfloat16*)d_ws;     // n*128 bf16
    float* pay  = (float*)(fsrcb + (size_t)n * 128);   // ne*8 f (32B payload)
    float* el   = pay + (size_t)ne * 8;                // n*4 f
    float* er   = el + (size_t)n * 4;                  // n*4 f
    float* eet  = er + (size_t)n * 4;                  // 32 f
    int* deg    = (int*)(eet + 32);                    // n i
    int* offs   = deg + n;                             // n+1 i
    int* cursor = offs + n + 1;                        // n i
    int* bsum   = cursor + n;                          // <=1024 i

    float* rst  = (float*)d_out;                       // n*128
    float* aBuf = rst + (size_t)n * 128;               // ne*4 (final a)

    const int nb = (n + SC_ELEMS - 1) / SC_ELEMS;

    hipMemsetAsync(deg, 0, (size_t)n * sizeof(int), stream);

    k_proj<<<512, 256, 0, stream>>>(feat, W_fc, fsrcb, attn_l, attn_r, ntype, el, er, n);
    k_deg<<<(ne + 255) / 256, 256, 0, stream>>>(dst, deg, ne, W_e, edge_emb, attn_e, eet);
    k_scan_sum<<<nb, 256, 0, stream>>>(deg, bsum, n);
    k_scan_mid<<<1, 1024, 0, stream>>>(bsum, nb);
    k_scan_out<<<nb, 256, 0, stream>>>(deg, bsum, offs, cursor, n);
    k_edge<<<(ne + 255) / 256, 256, 0, stream>>>(src, dst, etype, el, er, eet, cursor, pay, ne);
    k_aggfull<<<n, 128, 0, stream>>>(offs, pay, fsrcb, aBuf, rst);
}